// Round 11
// baseline (186.049 us; speedup 1.0000x reference)
//
#include <hip/hip_runtime.h>
#include <hip/hip_fp16.h>

constexpr int R = 1024;
constexpr int C = 4096;
constexpr int N_CELLS = 8192;

constexpr unsigned T1    = 8u;       // tier-1 uniform cap (4 pair-iters)
constexpr unsigned OVCAP = 12288u;   // overflow list capacity (expect ~1300)

// Workspace (u32 indices):
//   [0,4096)   cursor      (per-col entry count)
//   [4096)     ovcur       (overflow cursor, padded to 16)
//   [4112,...) ov          (2*OVCAP words: {col|oa<<16, ob} pairs)
//   e3         tier-1 lists: 64 windows * 512 words, pair-interleaved
constexpr size_t WS_CURSOR = 0;
constexpr size_t WS_OVCUR  = 4096;
constexpr size_t WS_OV     = 4112;
constexpr size_t WS_E3     = 4112 + 2 * OVCAP;

__device__ inline __half2 h2(unsigned u) { return *reinterpret_cast<__half2*>(&u); }

__device__ inline uint2 packh4(float v0, float v1, float v2, float v3) {
    __half2 h01 = __float22half2_rn(make_float2(v0, v1));
    __half2 h23 = __float22half2_rn(make_float2(v2, v3));
    uint2 u;
    u.x = *reinterpret_cast<unsigned*>(&h01);
    u.y = *reinterpret_cast<unsigned*>(&h23);
    return u;
}

// fp16x2 add into LDS via CAS (guaranteed-compile; volume is tiny: ~3 wave-iters/block)
__device__ inline void lds_pk_add(unsigned* addr, __half2 v) {
    unsigned old = *addr, assumed;
    do {
        assumed = old;
        __half2 cur = h2(assumed);
        __half2 nv = __hadd2(cur, v);
        old = atomicCAS(addr, assumed, *reinterpret_cast<unsigned*>(&nv));
    } while (old != assumed);
}

// ---- prep: write first T1 entries per column into fixed padded slots;
// spill the rest into a single pooled overflow list ----
__global__ void fill_kernel(const int* __restrict__ i0, const int* __restrict__ i1,
                            const int* __restrict__ i2, unsigned* __restrict__ cursor,
                            unsigned* __restrict__ ovcur, unsigned* __restrict__ ov,
                            unsigned* __restrict__ e3) {
    const int n = blockIdx.x * 256 + threadIdx.x;
    if (n < N_CELLS) {
        const unsigned a = (unsigned)i0[n], b = (unsigned)i1[n], c = (unsigned)i2[n];
        auto put = [&](unsigned col, unsigned oa, unsigned ob) {
            const unsigned i = atomicAdd(&cursor[col], 1u);
            if (i < T1) {
                e3[(col >> 6) * 512u + (i >> 1) * 128u + (col & 63u) * 2u + (i & 1u)]
                    = oa | (ob << 16);
            } else {
                const unsigned j = atomicAdd(ovcur, 1u);
                if (j < OVCAP) {
                    ov[2u * j]     = col | (oa << 16);
                    ov[2u * j + 1] = ob;
                }
            }
        };
        put(a, b, c);
        put(b, a, c);
        put(c, a, b);
    }
}

// ---- main: one block per r, 512 threads, 2 blocks/CU (LDS 64 KiB).
// sh[0..4095] = rows fp16x4-packed; sh[4096..8191] = p1 overflow accumulator.
// Tier-1: uniform 4 pair-iters/col, invalid slots masked via cndmask.
// Tier-2: pooled overflow walked cooperatively, fp16x2 CAS-adds into p1.
__global__ __launch_bounds__(512, 4) void gather_kernel(
    const float* __restrict__ in,
    const unsigned* __restrict__ cursor,
    const unsigned* __restrict__ ovcur,
    const unsigned* __restrict__ ov,
    const unsigned* __restrict__ e3,
    float* __restrict__ out)
{
    __shared__ uint2 sh[2 * C];   // 64 KiB exactly

    const int r = blockIdx.x;
    const int t = threadIdx.x;

    const float* __restrict__ p0r = in + ((size_t)0 * R + r) * C;
    const float* __restrict__ p1r = in + ((size_t)1 * R + r) * C;
    const float* __restrict__ p2r = in + ((size_t)2 * R + r) * C;
    const float* __restrict__ p3r = in + ((size_t)3 * R + r) * C;

    // Stage rows + zero p1.
    #pragma unroll
    for (int j = 0; j < 2; ++j) {
        const int c = t * 8 + j * 4;
        const float4 a = *reinterpret_cast<const float4*>(p0r + c);
        const float4 b = *reinterpret_cast<const float4*>(p1r + c);
        const float4 d = *reinterpret_cast<const float4*>(p2r + c);
        const float4 g = *reinterpret_cast<const float4*>(p3r + c);
        sh[c + 0] = packh4(a.x, b.x, d.x, g.x);
        sh[c + 1] = packh4(a.y, b.y, d.y, g.y);
        sh[c + 2] = packh4(a.z, b.z, d.z, g.z);
        sh[c + 3] = packh4(a.w, b.w, d.w, g.w);
    }
    #pragma unroll
    for (int j = 0; j < 8; ++j)
        sh[C + t + 512 * j] = make_uint2(0u, 0u);
    __syncthreads();

    const unsigned wave = (unsigned)t >> 6;
    const unsigned lane = (unsigned)t & 63u;

    __half2 acc01[8], acc23[8];
    unsigned vk[8];

    // ---- tier-1 ----
    #pragma unroll
    for (int k = 0; k < 8; ++k) {
        const unsigned w = wave * 8u + (unsigned)k;
        const unsigned c = w * 64u + lane;
        unsigned v = cursor[c];
        if (v > T1) v = T1;
        vk[k] = v;
        const uint2* __restrict__ lst2 =
            reinterpret_cast<const uint2*>(e3 + w * 512u) + lane;

        __half2 a01 = __float2half2_rn(0.f), a23 = a01;

        #pragma unroll
        for (unsigned j = 0; j < 4; ++j) {
            const uint2 pw = lst2[j * 64u];
            // entry 2j
            uint2 A0 = sh[pw.x & 4095u];
            const uint2 B0 = sh[(pw.x >> 16) & 4095u];
            if (2u * j >= v) { A0.x = 0u; A0.y = 0u; }   // cndmask: zero operand
            a01 = __hfma2(h2(A0.x), h2(B0.x), a01);
            a23 = __hfma2(h2(A0.y), h2(B0.y), a23);
            // entry 2j+1
            uint2 A1 = sh[pw.y & 4095u];
            const uint2 B1 = sh[(pw.y >> 16) & 4095u];
            if (2u * j + 1u >= v) { A1.x = 0u; A1.y = 0u; }
            a01 = __hfma2(h2(A1.x), h2(B1.x), a01);
            a23 = __hfma2(h2(A1.y), h2(B1.y), a23);
        }
        acc01[k] = a01;
        acc23[k] = a23;
    }

    // ---- tier-2: pooled overflow ----
    {
        unsigned nov = *ovcur;
        if (nov > OVCAP) nov = OVCAP;
        const uint2* __restrict__ ov2 = reinterpret_cast<const uint2*>(ov);
        for (unsigned i = (unsigned)t; i < nov; i += 512u) {
            const uint2 e = ov2[i];
            const unsigned tc = e.x & 4095u;
            const unsigned oa = (e.x >> 16) & 4095u;
            const unsigned ob = e.y & 4095u;
            const uint2 A = sh[oa];
            const uint2 B = sh[ob];
            const __half2 p01 = __hmul2(h2(A.x), h2(B.x));
            const __half2 p23 = __hmul2(h2(A.y), h2(B.y));
            unsigned* base = reinterpret_cast<unsigned*>(&sh[C + tc]);
            lds_pk_add(base + 0, p01);
            lds_pk_add(base + 1, p23);
        }
    }
    __syncthreads();

    // ---- epilogue: coalesced stores ----
    #pragma unroll
    for (int k = 0; k < 8; ++k) {
        const unsigned w = wave * 8u + (unsigned)k;
        const unsigned c = w * 64u + lane;
        const uint2 pr = sh[C + c];
        const uint2 ow = sh[c];
        const __half2 t01 = __hadd2(acc01[k], h2(pr.x));
        const __half2 t23 = __hadd2(acc23[k], h2(pr.y));
        const float2 f01 = __half22float2(t01);
        const float2 f23 = __half22float2(t23);
        const float2 o01 = __half22float2(h2(ow.x));
        const float2 o23 = __half22float2(h2(ow.y));

        __builtin_nontemporal_store(o01.x * f01.x, out + ((size_t)0 * R + r) * C + c);
        __builtin_nontemporal_store(o01.y * f01.y, out + ((size_t)1 * R + r) * C + c);
        __builtin_nontemporal_store(o23.x * f23.x, out + ((size_t)2 * R + r) * C + c);
        __builtin_nontemporal_store(o23.y * f23.y, out + ((size_t)3 * R + r) * C + c);
        __builtin_nontemporal_store(f01.x,         out + ((size_t)4 * R + r) * C + c);
        __builtin_nontemporal_store(f01.y,         out + ((size_t)5 * R + r) * C + c);
        __builtin_nontemporal_store(f23.x,         out + ((size_t)6 * R + r) * C + c);
        __builtin_nontemporal_store(f23.y,         out + ((size_t)7 * R + r) * C + c);
    }
}

extern "C" void kernel_launch(void* const* d_in, const int* in_sizes, int n_in,
                              void* d_out, int out_size, void* d_ws, size_t ws_size,
                              hipStream_t stream) {
    const float* in   = (const float*)d_in[0];
    const int*   idx0 = (const int*)d_in[1];
    const int*   idx1 = (const int*)d_in[2];
    const int*   idx2 = (const int*)d_in[3];
    float* out = (float*)d_out;

    unsigned* ws     = (unsigned*)d_ws;
    unsigned* cursor = ws + WS_CURSOR;
    unsigned* ovcur  = ws + WS_OVCUR;
    unsigned* ov     = ws + WS_OV;
    unsigned* e3     = ws + WS_E3;

    // zero cursor + ovcur (contiguous); e3/ov are masked/bounded, no zeroing
    hipMemsetAsync(cursor, 0, (4096 + 16) * sizeof(unsigned), stream);

    fill_kernel<<<dim3((N_CELLS + 255) / 256), dim3(256), 0, stream>>>(
        idx0, idx1, idx2, cursor, ovcur, ov, e3);
    gather_kernel<<<dim3(R), dim3(512), 0, stream>>>(in, cursor, ovcur, ov, e3, out);
}

// Round 12
// 57.363 us; speedup vs baseline: 3.2434x; 3.2434x over previous
//
#include <hip/hip_runtime.h>
#include <hip/hip_fp16.h>

constexpr int R = 1024;
constexpr int C = 4096;
constexpr int N_CELLS = 8192;

constexpr unsigned T1      = 8u;          // uniform tier-1 entries per column
constexpr unsigned OVCAP   = 8192u;       // overflow entry capacity (expect ~1300)
constexpr unsigned SLOTCAP = 1023u;       // overflow column slots (expect ~600)
constexpr unsigned NONE    = 0xFFFFFFFFu;

// LDS layout: sh[0..4095] = rows (fp16x4/col), sh[4096..5119] = overflow slots.
// sh[5119] (slot 1023) is the permanent zero sentinel.
constexpr unsigned SENT      = 5119u;
constexpr unsigned PAD_ENTRY = SENT | (SENT << 13);

// Workspace (u32 indices)
constexpr size_t WS_CURSOR  = 0;                     // 4096 per-col counts
constexpr size_t WS_OVCUR   = 4096;                  // overflow entry cursor
constexpr size_t WS_SLOTCTR = 4097;                  // overflow slot counter
constexpr size_t WS_OV      = 4112;                  // 2*OVCAP words {col|oa<<16, ob}
constexpr size_t WS_SLOTMAP = 4112 + 2 * OVCAP;      // 4096 col -> slot (or NONE)
constexpr size_t WS_E3      = WS_SLOTMAP + 4096;     // 64 windows * 512 words

__device__ inline __half2 h2(unsigned u) { return *reinterpret_cast<__half2*>(&u); }

__device__ inline uint2 packh4(float v0, float v1, float v2, float v3) {
    __half2 h01 = __float22half2_rn(make_float2(v0, v1));
    __half2 h23 = __float22half2_rn(make_float2(v2, v3));
    uint2 u;
    u.x = *reinterpret_cast<unsigned*>(&h01);
    u.y = *reinterpret_cast<unsigned*>(&h23);
    return u;
}

// fp16x2 add into LDS via CAS (tiny volume: ~1300 entries total per block)
__device__ inline void lds_pk_add(unsigned* addr, __half2 v) {
    unsigned old = *addr, assumed;
    do {
        assumed = old;
        __half2 cur = h2(assumed);
        __half2 nv = __hadd2(cur, v);
        old = atomicCAS(addr, assumed, *reinterpret_cast<unsigned*>(&nv));
    } while (old != assumed);
}

// ---- prep 1: first T1 entries per col into fixed slots; rest into pooled ov ----
__global__ void fill_kernel(const int* __restrict__ i0, const int* __restrict__ i1,
                            const int* __restrict__ i2, unsigned* __restrict__ cursor,
                            unsigned* __restrict__ ovcur, unsigned* __restrict__ ov,
                            unsigned* __restrict__ e3) {
    const int n = blockIdx.x * 256 + threadIdx.x;
    if (n < N_CELLS) {
        const unsigned a = (unsigned)i0[n], b = (unsigned)i1[n], c = (unsigned)i2[n];
        auto put = [&](unsigned col, unsigned oa, unsigned ob) {
            const unsigned i = atomicAdd(&cursor[col], 1u);
            if (i < T1) {
                e3[(col >> 6) * 512u + (i >> 1) * 128u + (col & 63u) * 2u + (i & 1u)]
                    = oa | (ob << 13);
            } else {
                const unsigned j = atomicAdd(ovcur, 1u);
                if (j < OVCAP) {
                    ov[2u * j]     = col | (oa << 16);
                    ov[2u * j + 1] = ob;
                }
            }
        };
        put(a, b, c);
        put(b, a, c);
        put(c, a, b);
    }
}

// ---- prep 2: pad unfilled tier-1 slots with the sentinel; assign overflow slots ----
__global__ __launch_bounds__(256) void pad_kernel(const unsigned* __restrict__ cursor,
                                                  unsigned* __restrict__ slotctr,
                                                  unsigned* __restrict__ slotmap,
                                                  unsigned* __restrict__ e3) {
    const unsigned c = blockIdx.x * 256u + threadIdx.x;
    const unsigned cnt = cursor[c];
    unsigned slot = NONE;
    if (cnt > T1) {
        const unsigned s = atomicAdd(slotctr, 1u);
        if (s < SLOTCAP) slot = s;
    }
    slotmap[c] = slot;
    const unsigned base = (c >> 6) * 512u + (c & 63u) * 2u;
    for (unsigned i = (cnt < T1 ? cnt : T1); i < T1; ++i)
        e3[base + (i >> 1) * 128u + (i & 1u)] = PAD_ENTRY;
}

// ---- main: one block per r, 512 threads, 40 KiB LDS -> 4 blocks/CU.
// Phase A: stage rows + zero slots. Phase B: overflow entries -> LDS slots (CAS).
// Phase C: per window, static 8-entry tier-1 + slot merge + stores (R8 structure,
// per-window register scope only -- no arrays live across phases).
__global__ __launch_bounds__(512, 8) void gather_kernel(
    const float* __restrict__ in,
    const unsigned* __restrict__ ovcur,
    const unsigned* __restrict__ ov,
    const unsigned* __restrict__ slotmap,
    const unsigned* __restrict__ e3,
    float* __restrict__ out)
{
    __shared__ uint2 sh[5120];   // 40960 B exactly

    const int r = blockIdx.x;
    const int t = threadIdx.x;

    const float* __restrict__ p0r = in + ((size_t)0 * R + r) * C;
    const float* __restrict__ p1r = in + ((size_t)1 * R + r) * C;
    const float* __restrict__ p2r = in + ((size_t)2 * R + r) * C;
    const float* __restrict__ p3r = in + ((size_t)3 * R + r) * C;

    // Phase A: stage rows fp16x4-packed; zero the slot region.
    #pragma unroll
    for (int j = 0; j < 2; ++j) {
        const int c = t * 8 + j * 4;
        const float4 a = *reinterpret_cast<const float4*>(p0r + c);
        const float4 b = *reinterpret_cast<const float4*>(p1r + c);
        const float4 d = *reinterpret_cast<const float4*>(p2r + c);
        const float4 g = *reinterpret_cast<const float4*>(p3r + c);
        sh[c + 0] = packh4(a.x, b.x, d.x, g.x);
        sh[c + 1] = packh4(a.y, b.y, d.y, g.y);
        sh[c + 2] = packh4(a.z, b.z, d.z, g.z);
        sh[c + 3] = packh4(a.w, b.w, d.w, g.w);
    }
    sh[4096 + t]       = make_uint2(0u, 0u);
    sh[4096 + 512 + t] = make_uint2(0u, 0u);
    __syncthreads();

    // Phase B: pooled overflow -> LDS slots.
    {
        unsigned nov = *ovcur;
        if (nov > OVCAP) nov = OVCAP;
        const uint2* __restrict__ ov2 = reinterpret_cast<const uint2*>(ov);
        for (unsigned i = (unsigned)t; i < nov; i += 512u) {
            const uint2 e = ov2[i];
            const unsigned col = e.x & 4095u;
            const unsigned oa  = (e.x >> 16) & 4095u;
            const unsigned ob  = e.y & 4095u;
            const uint2 A = sh[oa];
            const uint2 B = sh[ob];
            const __half2 p01 = __hmul2(h2(A.x), h2(B.x));
            const __half2 p23 = __hmul2(h2(A.y), h2(B.y));
            const unsigned s = slotmap[col];
            if (s < SLOTCAP) {
                unsigned* bp = reinterpret_cast<unsigned*>(&sh[4096 + s]);
                lds_pk_add(bp + 0, p01);
                lds_pk_add(bp + 1, p23);
            }
        }
    }
    __syncthreads();

    const unsigned wave = (unsigned)t >> 6;
    const unsigned lane = (unsigned)t & 63u;

    // Phase C: tier-1 (static 8 entries) + merge + store, per window.
#define ENT(WORD, A01, A23) {                                   \
        const uint2 A_ = sh[(WORD) & 8191u];                    \
        const uint2 B_ = sh[((WORD) >> 13) & 8191u];            \
        A01 = __hfma2(h2(A_.x), h2(B_.x), A01);                 \
        A23 = __hfma2(h2(A_.y), h2(B_.y), A23); }

    #pragma unroll
    for (int k = 0; k < 8; ++k) {
        const unsigned w = wave * 8u + (unsigned)k;
        const unsigned c = w * 64u + lane;
        const uint2* __restrict__ lst2 =
            reinterpret_cast<const uint2*>(e3 + w * 512u) + lane;

        const uint2 q0 = lst2[0];
        const uint2 q1 = lst2[64];
        const uint2 q2 = lst2[128];
        const uint2 q3 = lst2[192];

        __half2 aA01 = __float2half2_rn(0.f), aA23 = aA01;
        __half2 aB01 = aA01, aB23 = aA01;

        ENT(q0.x, aA01, aA23) ENT(q0.y, aB01, aB23)
        ENT(q1.x, aA01, aA23) ENT(q1.y, aB01, aB23)
        ENT(q2.x, aA01, aA23) ENT(q2.y, aB01, aB23)
        ENT(q3.x, aA01, aA23) ENT(q3.y, aB01, aB23)

        // merge overflow slot (branchless: NONE -> sentinel slot 1023 = zero)
        unsigned s = slotmap[c];
        if (s > SLOTCAP) s = SLOTCAP;
        const uint2 pr = sh[4096 + s];

        const __half2 s01 = __hadd2(__hadd2(aA01, aB01), h2(pr.x));
        const __half2 s23 = __hadd2(__hadd2(aA23, aB23), h2(pr.y));
        const float2 f01 = __half22float2(s01);
        const float2 f23 = __half22float2(s23);

        const uint2 ownp = sh[c];
        const float2 o01 = __half22float2(h2(ownp.x));
        const float2 o23 = __half22float2(h2(ownp.y));

        __builtin_nontemporal_store(o01.x * f01.x, out + ((size_t)0 * R + r) * C + c);
        __builtin_nontemporal_store(o01.y * f01.y, out + ((size_t)1 * R + r) * C + c);
        __builtin_nontemporal_store(o23.x * f23.x, out + ((size_t)2 * R + r) * C + c);
        __builtin_nontemporal_store(o23.y * f23.y, out + ((size_t)3 * R + r) * C + c);
        __builtin_nontemporal_store(f01.x,         out + ((size_t)4 * R + r) * C + c);
        __builtin_nontemporal_store(f01.y,         out + ((size_t)5 * R + r) * C + c);
        __builtin_nontemporal_store(f23.x,         out + ((size_t)6 * R + r) * C + c);
        __builtin_nontemporal_store(f23.y,         out + ((size_t)7 * R + r) * C + c);
    }
#undef ENT
}

extern "C" void kernel_launch(void* const* d_in, const int* in_sizes, int n_in,
                              void* d_out, int out_size, void* d_ws, size_t ws_size,
                              hipStream_t stream) {
    const float* in   = (const float*)d_in[0];
    const int*   idx0 = (const int*)d_in[1];
    const int*   idx1 = (const int*)d_in[2];
    const int*   idx2 = (const int*)d_in[3];
    float* out = (float*)d_out;

    unsigned* ws      = (unsigned*)d_ws;
    unsigned* cursor  = ws + WS_CURSOR;
    unsigned* ovcur   = ws + WS_OVCUR;
    unsigned* slotctr = ws + WS_SLOTCTR;
    unsigned* ov      = ws + WS_OV;
    unsigned* slotmap = ws + WS_SLOTMAP;
    unsigned* e3      = ws + WS_E3;

    // zero cursor + ovcur + slotctr (contiguous prefix)
    hipMemsetAsync(ws, 0, 4112 * sizeof(unsigned), stream);

    fill_kernel<<<dim3((N_CELLS + 255) / 256), dim3(256), 0, stream>>>(
        idx0, idx1, idx2, cursor, ovcur, ov, e3);
    pad_kernel<<<dim3(C / 256), dim3(256), 0, stream>>>(cursor, slotctr, slotmap, e3);
    gather_kernel<<<dim3(R), dim3(512), 0, stream>>>(in, ovcur, ov, slotmap, e3, out);
}